// Round 5
// baseline (1852.038 us; speedup 1.0000x reference)
//
#include <hip/hip_runtime.h>

#define NP 131072   // points
#define DD 128      // dims (GEMM K)
#define KK 256      // clusters (GEMM N)
#define MAXIT 8
#define TOLSQ (1e-4f * 1e-4f)
#define NSUB 8      // per-cluster sum split for load balance / occupancy

typedef _Float16 half8 __attribute__((ext_vector_type(8)));
typedef float f32x4 __attribute__((ext_vector_type(4)));

// ws re-poisoned 0xAA before every timed call — every field below is written
// before it is read on every kernel_launch.
struct Ws {
    float C[KK * DD];
    float newC[KK * DD];
    float cnorm[KK];
    float shiftsq;
    int done;
    int ilab[NP];              // labels (int)
    int order[NP];             // point indices sorted by label
    int counts[KK];            // per-cluster sizes (int, exact)
    int cursor[KK];            // scatter cursors (zeroed each iter)
    float psums[NSUB * KK * DD];  // non-atomic per-sub partial sums
    // fp16 hi/lo planes, pre-swizzled into MFMA fragment order (16B aligned)
    alignas(16) _Float16 Csh[KK * DD];
    alignas(16) _Float16 Csl[KK * DD];
    alignas(16) _Float16 Xsh[(size_t)NP * DD];
    alignas(16) _Float16 Xsl[(size_t)NP * DD];
};

// C0 = X[init_idx]; zero done flag.  grid: KK x DD
__global__ void k_init(const float* __restrict__ X, const int* __restrict__ idx,
                       float* __restrict__ C, int* __restrict__ done) {
    int k = blockIdx.x, d = threadIdx.x;
    C[k * DD + d] = X[(size_t)idx[k] * DD + d];
    if (k == 0 && d == 0) *done = 0;
}

// Once per call: split X into fp16 hi/lo planes in A-fragment order.
// A-frag (16x16x32 f16): lane L of the wave owning 16-point group g16 at
// k-step ks holds X[g16*16 + (L&15)][ks*32 + (L>>4)*8 + j], j=0..7.
// Flat: Xs[(((g16*4)+ks)*64 + L)*8 + j].  grid: NP*DD/8/256 = 8192 blocks.
__global__ void k_split(const float* __restrict__ X, _Float16* __restrict__ Xh,
                        _Float16* __restrict__ Xl) {
    size_t idx = (size_t)blockIdx.x * 256 + threadIdx.x;  // one per 8 elems
    int lane = idx & 63;
    size_t g16k = idx >> 6;
    size_t point = (g16k >> 2) * 16 + (lane & 15);
    int dim0 = (int)(g16k & 3) * 32 + (lane >> 4) * 8;
    const f32x4* s4 = (const f32x4*)(X + point * DD + dim0);
    f32x4 a = s4[0], b = s4[1];
    half8 h, l;
#pragma unroll
    for (int j = 0; j < 4; j++) {
        _Float16 hi = (_Float16)a[j];
        h[j] = hi; l[j] = (_Float16)(a[j] - (float)hi);
    }
#pragma unroll
    for (int j = 0; j < 4; j++) {
        _Float16 hi = (_Float16)b[j];
        h[4 + j] = hi; l[4 + j] = (_Float16)(b[j] - (float)hi);
    }
    *(half8*)(Xh + idx * 8) = h;
    *(half8*)(Xl + idx * 8) = l;
}

// Initial prep: cnorm + hi/lo B-fragment planes for C0; zero counts/cursor.
// B-frag: lane L at (ks, cluster-tile ct) holds C[ct*16+(L&15)][ks*32+(L>>4)*8+j]
// -> flat ((ks*16+ct)*64 + L)*8 + j.  grid: KK x DD
__global__ void k_prep0(const float* __restrict__ C, float* __restrict__ cnorm,
                        _Float16* __restrict__ Ch, _Float16* __restrict__ Cl,
                        int* __restrict__ counts, int* __restrict__ cursor) {
    int k = blockIdx.x, d = threadIdx.x;
    float v = C[k * DD + d];
    _Float16 hi = (_Float16)v;
    int ct = k >> 4, l4 = k & 15, ks = d >> 5, q = (d >> 3) & 3, j = d & 7;
    size_t dst = ((size_t)(ks * 16 + ct) * 64 + (q * 16 + l4)) * 8 + j;
    Ch[dst] = hi;
    Cl[dst] = (_Float16)(v - (float)hi);
    __shared__ float red[DD];
    red[d] = v * v;
    __syncthreads();
    for (int s = DD / 2; s > 0; s >>= 1) {
        if (d < s) red[d] += red[d + s];
        __syncthreads();
    }
    if (d == 0) {
        cnorm[k] = red[0];
        counts[k] = 0;
        cursor[k] = 0;
    }
}

// MFMA assignment + per-block label histogram -> global counts.
// Each wave = 32 points x 256 clusters, fp16 hi/lo 3-term split, fp32 acc.
// Also zeroes shiftsq (stream-ordered: previous upprep already consumed it).
// grid: NP/128 x 256.
__global__ __launch_bounds__(256, 2) void k_assign(
    const _Float16* __restrict__ Xh, const _Float16* __restrict__ Xl,
    const _Float16* __restrict__ Ch, const _Float16* __restrict__ Cl,
    const float* __restrict__ cnorm, float* __restrict__ outlab,
    int* __restrict__ ilab, int* __restrict__ counts,
    float* __restrict__ shiftsq) {
    __shared__ int hist[KK];
    if (blockIdx.x == 0 && threadIdx.x == 0) *shiftsq = 0.0f;
    hist[threadIdx.x] = 0;

    const int wave = threadIdx.x >> 6;
    const int lane = threadIdx.x & 63;
    const int l4 = lane & 15, g = lane >> 4;
    const int g16 = blockIdx.x * 8 + wave * 2;

    f32x4 acc[2][16];
#pragma unroll
    for (int pg = 0; pg < 2; pg++)
#pragma unroll
        for (int ct = 0; ct < 16; ct++) acc[pg][ct] = (f32x4){0.f, 0.f, 0.f, 0.f};

#pragma unroll
    for (int ks = 0; ks < 4; ks++) {
        const size_t a0 = ((size_t)(g16 * 4 + ks) * 64 + lane) * 8;
        const size_t a1 = ((size_t)((g16 + 1) * 4 + ks) * 64 + lane) * 8;
        half8 ah0 = *(const half8*)(Xh + a0);
        half8 al0 = *(const half8*)(Xl + a0);
        half8 ah1 = *(const half8*)(Xh + a1);
        half8 al1 = *(const half8*)(Xl + a1);
#pragma unroll
        for (int ct = 0; ct < 16; ct++) {
            const size_t bo = ((size_t)(ks * 16 + ct) * 64 + lane) * 8;
            half8 bh = *(const half8*)(Ch + bo);
            half8 bl = *(const half8*)(Cl + bo);
            acc[0][ct] = __builtin_amdgcn_mfma_f32_16x16x32_f16(al0, bh, acc[0][ct], 0, 0, 0);
            acc[0][ct] = __builtin_amdgcn_mfma_f32_16x16x32_f16(ah0, bl, acc[0][ct], 0, 0, 0);
            acc[0][ct] = __builtin_amdgcn_mfma_f32_16x16x32_f16(ah0, bh, acc[0][ct], 0, 0, 0);
            acc[1][ct] = __builtin_amdgcn_mfma_f32_16x16x32_f16(al1, bh, acc[1][ct], 0, 0, 0);
            acc[1][ct] = __builtin_amdgcn_mfma_f32_16x16x32_f16(ah1, bl, acc[1][ct], 0, 0, 0);
            acc[1][ct] = __builtin_amdgcn_mfma_f32_16x16x32_f16(ah1, bh, acc[1][ct], 0, 0, 0);
        }
    }

    float cn[16];
#pragma unroll
    for (int ct = 0; ct < 16; ct++) cn[ct] = cnorm[ct * 16 + l4];

    // Packed argmin keys: (monotone(float) << 32) | cluster. NaN -> -inf so
    // NaN beats all finite values; low bits give np's first-index tie-break.
    unsigned long long best[2][4];
#pragma unroll
    for (int pg = 0; pg < 2; pg++)
#pragma unroll
        for (int r = 0; r < 4; r++) best[pg][r] = ~0ull;

#pragma unroll
    for (int pg = 0; pg < 2; pg++)
#pragma unroll
        for (int ct = 0; ct < 16; ct++)
#pragma unroll
            for (int r = 0; r < 4; r++) {
                float s = fmaf(-2.0f, acc[pg][ct][r], cn[ct]);
                if (__builtin_isnan(s)) s = -__builtin_inff();
                unsigned u = __float_as_uint(s);
                unsigned m = (u >> 31) ? ~u : (u ^ 0x80000000u);
                unsigned long long key =
                    ((unsigned long long)m << 32) | (unsigned)(ct * 16 + l4);
                if (key < best[pg][r]) best[pg][r] = key;
            }

    // reduce over the 16 cluster-column lanes (low 4 lane bits)
#pragma unroll
    for (int d = 1; d < 16; d <<= 1)
#pragma unroll
        for (int pg = 0; pg < 2; pg++)
#pragma unroll
            for (int r = 0; r < 4; r++) {
                unsigned long long o = __shfl_xor(best[pg][r], d, 64);
                if (o < best[pg][r]) best[pg][r] = o;
            }

    __syncthreads();  // hist zero visible
    if (l4 == 0) {
#pragma unroll
        for (int pg = 0; pg < 2; pg++)
#pragma unroll
            for (int r = 0; r < 4; r++) {
                int point = blockIdx.x * 128 + wave * 32 + pg * 16 + g * 4 + r;
                int lbl = (int)(best[pg][r] & 0x1ff);
                outlab[point] = (float)lbl;
                ilab[point] = lbl;
                atomicAdd(&hist[lbl], 1);
            }
    }
    __syncthreads();
    int h = hist[threadIdx.x];
    if (h) atomicAdd(&counts[threadIdx.x], h);
}

// Scatter points into cluster-sorted order. Each block redundantly scans
// counts (256 ints) in LDS for exclusive offsets; position via cursor atomics.
// grid: NP/256 x 256
__global__ __launch_bounds__(256) void k_scatter(
    const int* __restrict__ ilab, const int* __restrict__ counts,
    int* __restrict__ cursor, int* __restrict__ order) {
    const int t = threadIdx.x;
    __shared__ int sc[KK];
    __shared__ int ex[KK];
    int c = counts[t];
    sc[t] = c;
    __syncthreads();
#pragma unroll
    for (int d = 1; d < KK; d <<= 1) {
        int v = (t >= d) ? sc[t - d] : 0;
        __syncthreads();
        sc[t] += v;
        __syncthreads();
    }
    ex[t] = sc[t] - c;  // exclusive prefix
    __syncthreads();

    int p = blockIdx.x * 256 + t;
    int l = ilab[p];
    int pos = ex[l] + atomicAdd(&cursor[l], 1);
    order[pos] = p;
}

// Per-cluster segmented sum over the sorted list: registers only, coalesced
// 512B row reads, zero atomics. Non-atomic partial write per (sub, k).
// grid: dim3(KK, NSUB) x 256  (256 thr = 2 points x 128 dims)
__global__ __launch_bounds__(256) void k_sum(
    const float* __restrict__ X, const int* __restrict__ order,
    const int* __restrict__ counts, float* __restrict__ psums) {
    const int k = blockIdx.x, sub = blockIdx.y;
    const int t = threadIdx.x;
    __shared__ int sc[KK];
    __shared__ int cc[KK];
    int c = counts[t];
    sc[t] = c;
    cc[t] = c;
    __syncthreads();
#pragma unroll
    for (int d = 1; d < KK; d <<= 1) {
        int v = (t >= d) ? sc[t - d] : 0;
        __syncthreads();
        sc[t] += v;
        __syncthreads();
    }
    const int off = sc[k] - cc[k];
    const int cnt = cc[k];
    const int lo = off + (int)(((long long)cnt * sub) / NSUB);
    const int hi = off + (int)(((long long)cnt * (sub + 1)) / NSUB);

    const int half = t >> 7, d = t & 127;
    float acc = 0.0f;
    for (int i = lo + half; i < hi; i += 2) {
        int pi = order[i];
        acc += X[(size_t)pi * DD + d];
    }
    __shared__ float comb[256];
    comb[t] = acc;
    __syncthreads();
    if (t < 128) psums[((size_t)sub * KK + k) * DD + t] = comb[t] + comb[t + 128];
}

// Reduce NSUB partials -> newC = sums/counts (0/0 -> NaN, matching jnp);
// shift^2 block-reduced, one atomic per block.  grid: KK*DD/256 x 256
__global__ void k_reduce(const float* __restrict__ psums, const int* __restrict__ counts,
                         const float* __restrict__ C, float* __restrict__ newC,
                         float* __restrict__ shiftsq) {
    const int g = blockIdx.x * 256 + threadIdx.x;
    const int k = g >> 7;
    const int t = threadIdx.x;

    float s = 0.0f;
#pragma unroll
    for (int sub = 0; sub < NSUB; sub++) s += psums[(size_t)sub * KK * DD + g];

    float nc = s / (float)counts[k];
    newC[g] = nc;
    float diff = nc - C[g];

    __shared__ float red[256];
    red[t] = diff * diff;
    __syncthreads();
    for (int st = 128; st > 0; st >>= 1) {
        if (t < st) red[t] += red[t + st];
        __syncthreads();
    }
    if (t == 0) atomicAdd(shiftsq, red[0]);
}

// Fused convergence check + centroid update + next-iter prep (cnorm + hi/lo
// planes) + zero counts/cursor. NaN shiftsq -> not converged (jnp match).
// Benign done race: all blocks compute the same nd.  grid: KK/2 x 256.
__global__ void k_upprep(const float* __restrict__ newC, float* __restrict__ C,
                         const float* __restrict__ shiftsq, int* __restrict__ done,
                         float* __restrict__ cnorm, _Float16* __restrict__ Ch,
                         _Float16* __restrict__ Cl, int* __restrict__ counts,
                         int* __restrict__ cursor) {
    const int t = threadIdx.x;
    const int k = blockIdx.x * 2 + (t >> 7);
    const int d = t & 127;
    float ss = *shiftsq;
    int nd = (*done != 0) || (ss < TOLSQ);
    float v = nd ? C[k * DD + d] : newC[k * DD + d];
    C[k * DD + d] = v;
    if (blockIdx.x == 0 && t == 0 && nd) *done = 1;
    if (d == 0) {
        counts[k] = 0;
        cursor[k] = 0;
    }

    _Float16 hi = (_Float16)v;
    int ct = k >> 4, l4 = k & 15, ks = d >> 5, q = (d >> 3) & 3, j = d & 7;
    size_t dst = ((size_t)(ks * 16 + ct) * 64 + (q * 16 + l4)) * 8 + j;
    Ch[dst] = hi;
    Cl[dst] = (_Float16)(v - (float)hi);

    __shared__ float red[256];
    red[t] = v * v;
    __syncthreads();
    for (int s = 64; s > 0; s >>= 1) {
        if ((t & 127) < s) red[t] += red[t + s];
        __syncthreads();
    }
    if (d == 0) cnorm[k] = red[t];
}

__global__ void k_final(const float* __restrict__ C, float* __restrict__ out) {
    int i = blockIdx.x * 256 + threadIdx.x;
    out[i] = C[i];
}

extern "C" void kernel_launch(void* const* d_in, const int* in_sizes, int n_in,
                              void* d_out, int out_size, void* d_ws, size_t ws_size,
                              hipStream_t stream) {
    const float* X = (const float*)d_in[0];
    const int* idx = (const int*)d_in[1];
    float* out = (float*)d_out;
    Ws* w = (Ws*)d_ws;

    k_init<<<KK, DD, 0, stream>>>(X, idx, w->C, &w->done);
    k_split<<<(int)((size_t)NP * DD / 8 / 256), 256, 0, stream>>>(X, w->Xsh, w->Xsl);
    k_prep0<<<KK, DD, 0, stream>>>(w->C, w->cnorm, w->Csh, w->Csl, w->counts, w->cursor);

    for (int it = 0; it < MAXIT; it++) {
        k_assign<<<NP / 128, 256, 0, stream>>>(w->Xsh, w->Xsl, w->Csh, w->Csl,
                                               w->cnorm, out, w->ilab, w->counts,
                                               &w->shiftsq);
        k_scatter<<<NP / 256, 256, 0, stream>>>(w->ilab, w->counts, w->cursor, w->order);
        k_sum<<<dim3(KK, NSUB), 256, 0, stream>>>(X, w->order, w->counts, w->psums);
        k_reduce<<<KK * DD / 256, 256, 0, stream>>>(w->psums, w->counts, w->C,
                                                    w->newC, &w->shiftsq);
        k_upprep<<<KK / 2, 256, 0, stream>>>(w->newC, w->C, &w->shiftsq, &w->done,
                                             w->cnorm, w->Csh, w->Csl, w->counts,
                                             w->cursor);
    }

    k_final<<<KK * DD / 256, 256, 0, stream>>>(w->C, out + NP);
}